// Round 7
// baseline (1824.207 us; speedup 1.0000x reference)
//
#include <hip/hip_runtime.h>
#include <math.h>

#define BB 256
#define TT 2048
#define FF 2
#define HH 128
#define OO 2
#define NT 1024   // 16 waves; col j = tid>>3 (8 threads/col, same wave)

typedef _Float16 h2 __attribute__((ext_vector_type(2)));

__device__ __forceinline__ float fast_rcp(float x) { return __builtin_amdgcn_rcpf(x); }
__device__ __forceinline__ float sigmoid_f(float x) { return fast_rcp(1.0f + __expf(-x)); }
__device__ __forceinline__ float tanh_f(float x) { return 1.0f - 2.0f * fast_rcp(1.0f + __expf(2.0f * x)); }

__device__ __forceinline__ float dot2(unsigned int hv, h2 w, float acc) {
#if __has_builtin(__builtin_amdgcn_fdot2)
    return __builtin_amdgcn_fdot2(__builtin_bit_cast(h2, hv), w, acc, false);
#else
    const h2 h = __builtin_bit_cast(h2, hv);
    acc = fmaf((float)h[0], (float)w[0], acc);
    return fmaf((float)h[1], (float)w[1], acc);
#endif
}

// 8 named h2 weights per gate (16 fp16 values = this thread's k-slice)
#define DECL8(P)  h2 P##0, P##1, P##2, P##3, P##4, P##5, P##6, P##7;
#define LDP(P, i, BASE) \
    P##i[0] = (_Float16)BASE[(kb + 2*(i)    ) * HH]; \
    P##i[1] = (_Float16)BASE[(kb + 2*(i) + 1) * HH];
#define LOAD8(P, BASE) \
    LDP(P,0,BASE) LDP(P,1,BASE) LDP(P,2,BASE) LDP(P,3,BASE) \
    LDP(P,4,BASE) LDP(P,5,BASE) LDP(P,6,BASE) LDP(P,7,BASE)
// 8 dot2 of one gate against the two h-chunks (single acc chain)
#define DOT8(P, C0, C1, ACC) \
    ACC = dot2(C0.x, P##0, ACC); ACC = dot2(C0.y, P##1, ACC); \
    ACC = dot2(C0.z, P##2, ACC); ACC = dot2(C0.w, P##3, ACC); \
    ACC = dot2(C1.x, P##4, ACC); ACC = dot2(C1.y, P##5, ACC); \
    ACC = dot2(C1.z, P##6, ACC); ACC = dot2(C1.w, P##7, ACC);

__global__ __launch_bounds__(NT, 4)
void gru_persistent(const float* __restrict__ x, const float* __restrict__ h0,
                    const float* __restrict__ Wir, const float* __restrict__ Wiz,
                    const float* __restrict__ Win, const float* __restrict__ Whr,
                    const float* __restrict__ Whz, const float* __restrict__ Whn,
                    const float* __restrict__ bhr, const float* __restrict__ bhz,
                    const float* __restrict__ bhn, const float* __restrict__ Wd,
                    const float* __restrict__ bd, float* __restrict__ out)
{
    // out layout: [carry B*H][y B*T*O]
    __shared__ float x_sh[TT * FF];                    // 16 KB
    __shared__ __align__(16) float    h_sh[HH];        // fp32 master h
    __shared__ __align__(16) _Float16 hh_sh[HH];       // fp16 copy for dots

    const int b    = blockIdx.x;
    const int tid  = threadIdx.x;
    const int j    = tid >> 3;          // output column 0..127
    const int ks   = tid & 7;           // k-octant (16 h values)
    const int kb   = ks * 16;           // k base
    const int wv   = tid >> 6;
    const int lane = tid & 63;
    const bool lead = (ks == 0);

    // --- per-thread weight slices: 24 h2 = 24 VGPRs, the whole point ---
    DECL8(wr) DECL8(wz) DECL8(wn)
    {
        const float* Wc;
        Wc = Whr + j; LOAD8(wr, Wc)
        Wc = Whz + j; LOAD8(wz, Wc)
        Wc = Whn + j; LOAD8(wn, Wc)
    }

    // leader extras (lane ks==0 of each column group)
    float br = 0.f, bz = 0.f, bn = 0.f;
    float wir0 = 0.f, wir1 = 0.f, wiz0 = 0.f, wiz1 = 0.f, win0 = 0.f, win1 = 0.f;
    if (lead) {
        br = bhr[j]; bz = bhz[j]; bn = bhn[j];
        wir0 = Wir[j]; wir1 = Wir[HH + j];
        wiz0 = Wiz[j]; wiz1 = Wiz[HH + j];
        win0 = Win[j]; win1 = Win[HH + j];
    }

    // wave 0 handles the tiny output projection y[t] = h @ Wd + bd
    float wdA0 = 0.f, wdA1 = 0.f, wdB0 = 0.f, wdB1 = 0.f, bd0 = 0.f, bd1 = 0.f;
    if (wv == 0) {
        wdA0 = Wd[lane * OO + 0];        wdA1 = Wd[lane * OO + 1];
        wdB0 = Wd[(lane + 64) * OO + 0]; wdB1 = Wd[(lane + 64) * OO + 1];
        bd0 = bd[0]; bd1 = bd[1];
    }

    // stage x row (exactly one float4 per thread) and h0
    {
        const float4* xi = reinterpret_cast<const float4*>(x + (size_t)b * TT * FF);
        reinterpret_cast<float4*>(x_sh)[tid] = xi[tid];
    }
    if (tid < HH) {
        const float hv = h0[b * HH + tid];
        h_sh[tid]  = hv;
        hh_sh[tid] = (_Float16)hv;
    }
    __syncthreads();

    float* __restrict__ yout = out + BB * HH;

    for (int t = 0; t < TT; ++t) {
        const float x0 = x_sh[t * FF + 0];
        const float x1 = x_sh[t * FF + 1];

        // h_old for this column (8 lanes same address -> LDS broadcast)
        const float hold = h_sh[j];

        // this thread's 16-half slice of h: two uint4 chunks
        const uint4* hq = reinterpret_cast<const uint4*>(hh_sh);
        const uint4 c0 = hq[ks * 2 + 0];
        const uint4 c1 = hq[ks * 2 + 1];

        float ra = 0.f, za = 0.f, ma = 0.f;
        DOT8(wr, c0, c1, ra)
        DOT8(wz, c0, c1, za)
        DOT8(wn, c0, c1, ma)

        // wave 0: emit y[t-1] from h_sh (stable during phase 1)
        if (wv == 0 && t > 0) {
            const float hv0 = h_sh[lane], hv1 = h_sh[lane + 64];
            float p0 = hv0 * wdA0 + hv1 * wdB0;
            float p1 = hv0 * wdA1 + hv1 * wdB1;
            #pragma unroll
            for (int off = 32; off >= 1; off >>= 1) {
                p0 += __shfl_xor(p0, off);
                p1 += __shfl_xor(p1, off);
            }
            if (lane == 0)
                reinterpret_cast<float2*>(yout)[(size_t)b * TT + (t - 1)] =
                    make_float2(p0 + bd0, p1 + bd1);
        }

        // in-wave 8-lane k-group reduction -> leader lane holds full dots
        #pragma unroll
        for (int m = 1; m <= 4; m <<= 1) {
            ra += __shfl_xor(ra, m);
            za += __shfl_xor(za, m);
            ma += __shfl_xor(ma, m);
        }

        __syncthreads();   // barrier A: all h reads done

        if (lead) {
            const float r  = sigmoid_f(ra + br + x0 * wir0 + x1 * wir1);
            const float z  = sigmoid_f(za + bz + x0 * wiz0 + x1 * wiz1);
            const float n  = tanh_f(x0 * win0 + x1 * win1 + r * (ma + bn));
            const float hn = (1.0f - z) * n + z * hold;
            h_sh[j]  = hn;
            hh_sh[j] = (_Float16)hn;
        }

        __syncthreads();   // barrier B: h_new visible
    }

    // tail: y[T-1] and carry
    if (wv == 0) {
        const float hv0 = h_sh[lane], hv1 = h_sh[lane + 64];
        float p0 = hv0 * wdA0 + hv1 * wdB0;
        float p1 = hv0 * wdA1 + hv1 * wdB1;
        #pragma unroll
        for (int off = 32; off >= 1; off >>= 1) {
            p0 += __shfl_xor(p0, off);
            p1 += __shfl_xor(p1, off);
        }
        if (lane == 0)
            reinterpret_cast<float2*>(yout)[(size_t)b * TT + (TT - 1)] =
                make_float2(p0 + bd0, p1 + bd1);
    }
    if (tid < HH) out[b * HH + tid] = h_sh[tid];
}

extern "C" void kernel_launch(void* const* d_in, const int* in_sizes, int n_in,
                              void* d_out, int out_size, void* d_ws, size_t ws_size,
                              hipStream_t stream) {
    const float* x   = (const float*)d_in[0];
    const float* h0  = (const float*)d_in[1];
    const float* Wir = (const float*)d_in[2];
    const float* Wiz = (const float*)d_in[3];
    const float* Win = (const float*)d_in[4];
    const float* Whr = (const float*)d_in[5];
    const float* Whz = (const float*)d_in[6];
    const float* Whn = (const float*)d_in[7];
    const float* bhr = (const float*)d_in[8];
    const float* bhz = (const float*)d_in[9];
    const float* bhn = (const float*)d_in[10];
    const float* Wd  = (const float*)d_in[11];
    const float* bd  = (const float*)d_in[12];
    float* out = (float*)d_out;

    gru_persistent<<<BB, NT, 0, stream>>>(x, h0, Wir, Wiz, Win, Whr, Whz, Whn,
                                          bhr, bhz, bhn, Wd, bd, out);
}

// Round 8
// 1641.476 us; speedup vs baseline: 1.1113x; 1.1113x over previous
//
#include <hip/hip_runtime.h>
#include <math.h>

#define BB 256
#define TT 2048
#define FF 2
#define HH 128
#define OO 2
#define NT 768   // 12 waves: 3 gates x 2 column-halves x 2 waves(128 threads)

// Dynamic LDS: x_sh (16 KB) + padding to exceed 80 KB so only ONE block fits
// per CU (160 KB pool). With 2-blocks/CU impossible, the register allocator
// has no occupancy incentive to spill the per-thread weight cache.
#define DYN_LDS_BYTES (90112)   // 88 KB

typedef _Float16 h2 __attribute__((ext_vector_type(2)));

__device__ __forceinline__ float fast_rcp(float x) { return __builtin_amdgcn_rcpf(x); }
__device__ __forceinline__ float sigmoid_f(float x) { return fast_rcp(1.0f + __expf(-x)); }
__device__ __forceinline__ float tanh_f(float x) { return 1.0f - 2.0f * fast_rcp(1.0f + __expf(2.0f * x)); }

__device__ __forceinline__ float dot2(unsigned int hv, h2 w, float acc) {
#if __has_builtin(__builtin_amdgcn_fdot2)
    return __builtin_amdgcn_fdot2(__builtin_bit_cast(h2, hv), w, acc, false);
#else
    const h2 h = __builtin_bit_cast(h2, hv);
    acc = fmaf((float)h[0], (float)w[0], acc);
    return fmaf((float)h[1], (float)w[1], acc);
#endif
}

// ---- 32 named packed-half2 weights: never an array, never address-taken ----
#define FORW32(M) \
  M(0)  M(1)  M(2)  M(3)  M(4)  M(5)  M(6)  M(7)  \
  M(8)  M(9)  M(10) M(11) M(12) M(13) M(14) M(15) \
  M(16) M(17) M(18) M(19) M(20) M(21) M(22) M(23) \
  M(24) M(25) M(26) M(27) M(28) M(29) M(30) M(31)

#define DECLW(i) h2 wp_##i;
#define LOADW(i) wp_##i[0] = (_Float16)Wcol[(c64 + 2*(i)    ) * HH]; \
                 wp_##i[1] = (_Float16)Wcol[(c64 + 2*(i) + 1) * HH];

// one uint4 LDS read = 8 halves of h -> 4 dot2 (8 MACs)
#define DOTQ(q, i0, i1, i2, i3)                       \
    {                                                 \
        const uint4 hv_ = hq[q];                      \
        a0 = dot2(hv_.x, wp_##i0, a0);                \
        a1 = dot2(hv_.y, wp_##i1, a1);                \
        a2 = dot2(hv_.z, wp_##i2, a2);                \
        a3 = dot2(hv_.w, wp_##i3, a3);                \
    }

__global__ __launch_bounds__(NT)
void gru_persistent(const float* __restrict__ x, const float* __restrict__ h0,
                    const float* __restrict__ Wir, const float* __restrict__ Wiz,
                    const float* __restrict__ Win, const float* __restrict__ Whr,
                    const float* __restrict__ Whz, const float* __restrict__ Whn,
                    const float* __restrict__ bhr, const float* __restrict__ bhz,
                    const float* __restrict__ bhn, const float* __restrict__ Wd,
                    const float* __restrict__ bd, float* __restrict__ out)
{
    // out layout: [carry B*H][y B*T*O]
    extern __shared__ __align__(16) float smem[];     // 88 KB: x_sh + pad
    float* x_sh = smem;                               // first 16 KB used
    __shared__ __align__(16) float    h_sh[HH];       // fp32 master h
    __shared__ __align__(16) _Float16 hh_sh[HH];      // fp16 copy for dots
    __shared__ float part[3][2][HH];                  // gate x half x j

    const int b    = blockIdx.x;
    const int tid  = threadIdx.x;
    const int g    = tid >> 8;          // 0:r 1:z 2:n   (4 waves per gate)
    const int c    = (tid >> 7) & 1;    // column half   (2 waves per half)
    const int j    = tid & (HH - 1);    // output column
    const int wv   = tid >> 6;          // wave id 0..11
    const int lane = tid & 63;
    const int c64  = c * 64;

    const float* Wh = (g == 0) ? Whr : (g == 1) ? Whz : Whn;
    const float* Wi = (g == 0) ? Wir : (g == 1) ? Wiz : Win;
    const float* bh = (g == 0) ? bhr : (g == 1) ? bhz : bhn;

    // half weight column, packed fp16: 32 VGPRs
    FORW32(DECLW)
    {
        const float* Wcol = Wh + j;     // column j, row stride HH
        FORW32(LOADW)
    }

    const float gbias = (c == 0) ? bh[j] : 0.0f;
    float wi0 = 0.0f, wi1 = 0.0f;
    if (c == 0 && g != 2) { wi0 = Wi[0 * HH + j]; wi1 = Wi[1 * HH + j]; }

    // combine-thread extras (tid < 128)
    float win0 = 0.0f, win1 = 0.0f;
    if (tid < HH) { win0 = Win[0 * HH + j]; win1 = Win[1 * HH + j]; }

    // y-wave (wave 8) extras: Wd columns for this lane's two h entries
    float wdA0 = 0.f, wdA1 = 0.f, wdB0 = 0.f, wdB1 = 0.f;
    if (wv == 8) {
        wdA0 = Wd[lane * OO + 0];        wdA1 = Wd[lane * OO + 1];
        wdB0 = Wd[(lane + 64) * OO + 0]; wdB1 = Wd[(lane + 64) * OO + 1];
    }
    const float bd0 = bd[0], bd1 = bd[1];

    // stage x row (float4) and h0 (fp32 + fp16 copy)
    {
        const float4* xi = reinterpret_cast<const float4*>(x + (size_t)b * TT * FF);
        float4* xo = reinterpret_cast<float4*>(x_sh);
        for (int i = tid; i < TT * FF / 4; i += NT) xo[i] = xi[i];
    }
    if (tid < HH) {
        const float hv = h0[b * HH + tid];
        h_sh[tid]  = hv;
        hh_sh[tid] = (_Float16)hv;
    }
    __syncthreads();

    float* __restrict__ yout = out + BB * HH;

    for (int t = 0; t < TT; ++t) {
        const float x0 = x_sh[t * FF + 0];
        const float x1 = x_sh[t * FF + 1];

        // ---- phase 1: per-gate half-column GEMV via v_dot2_f32_f16 ----
        float a0 = gbias + x0 * wi0 + x1 * wi1;   // wi==0 where not applicable
        float a1 = 0.f, a2 = 0.f, a3 = 0.f;
        // this thread's h slice: 64 halves = 8 x uint4 (uniform across wave)
        const uint4* hq = reinterpret_cast<const uint4*>(hh_sh) + (c << 3);
        DOTQ(0,  0,  1,  2,  3)
        DOTQ(1,  4,  5,  6,  7)
        DOTQ(2,  8,  9,  10, 11)
        DOTQ(3,  12, 13, 14, 15)
        DOTQ(4,  16, 17, 18, 19)
        DOTQ(5,  20, 21, 22, 23)
        DOTQ(6,  24, 25, 26, 27)
        DOTQ(7,  28, 29, 30, 31)
        part[g][c][j] = (a0 + a1) + (a2 + a3);

        // wave 8 additionally emits y[t-1] from h_sh (stable during phase 1)
        if (wv == 8 && t > 0) {
            const float hv0 = h_sh[lane], hv1 = h_sh[lane + 64];
            float p0 = hv0 * wdA0 + hv1 * wdB0;
            float p1 = hv0 * wdA1 + hv1 * wdB1;
            #pragma unroll
            for (int off = 32; off >= 1; off >>= 1) {
                p0 += __shfl_xor(p0, off);
                p1 += __shfl_xor(p1, off);
            }
            if (lane == 0)
                reinterpret_cast<float2*>(yout)[(size_t)b * TT + (t - 1)] =
                    make_float2(p0 + bd0, p1 + bd1);
        }
        __syncthreads();   // barrier A: partials visible

        // ---- phase 2: combine (threads 0..127), recurrence in fp32 ----
        if (tid < HH) {
            const float racc = part[0][0][j] + part[0][1][j];
            const float zacc = part[1][0][j] + part[1][1][j];
            const float macc = part[2][0][j] + part[2][1][j];
            const float r  = sigmoid_f(racc);
            const float z  = sigmoid_f(zacc);
            const float n  = tanh_f(x0 * win0 + x1 * win1 + r * macc);
            const float hn = (1.0f - z) * n + z * h_sh[j];
            h_sh[j]  = hn;
            hh_sh[j] = (_Float16)hn;
        }
        __syncthreads();   // barrier B: h_new visible
    }

    // tail: y[T-1] and carry
    if (wv == 8) {
        const float hv0 = h_sh[lane], hv1 = h_sh[lane + 64];
        float p0 = hv0 * wdA0 + hv1 * wdB0;
        float p1 = hv0 * wdA1 + hv1 * wdB1;
        #pragma unroll
        for (int off = 32; off >= 1; off >>= 1) {
            p0 += __shfl_xor(p0, off);
            p1 += __shfl_xor(p1, off);
        }
        if (lane == 0)
            reinterpret_cast<float2*>(yout)[(size_t)b * TT + (TT - 1)] =
                make_float2(p0 + bd0, p1 + bd1);
    }
    if (tid < HH) out[b * HH + tid] = h_sh[tid];
}

extern "C" void kernel_launch(void* const* d_in, const int* in_sizes, int n_in,
                              void* d_out, int out_size, void* d_ws, size_t ws_size,
                              hipStream_t stream) {
    const float* x   = (const float*)d_in[0];
    const float* h0  = (const float*)d_in[1];
    const float* Wir = (const float*)d_in[2];
    const float* Wiz = (const float*)d_in[3];
    const float* Win = (const float*)d_in[4];
    const float* Whr = (const float*)d_in[5];
    const float* Whz = (const float*)d_in[6];
    const float* Whn = (const float*)d_in[7];
    const float* bhr = (const float*)d_in[8];
    const float* bhz = (const float*)d_in[9];
    const float* bhn = (const float*)d_in[10];
    const float* Wd  = (const float*)d_in[11];
    const float* bd  = (const float*)d_in[12];
    float* out = (float*)d_out;

    // allow >64 KB dynamic LDS (host-side attribute; not a stream op,
    // graph-capture safe, idempotent)
    static_assert(DYN_LDS_BYTES > 80 * 1024, "pad must forbid 2 blocks/CU");
    hipFuncSetAttribute(reinterpret_cast<const void*>(gru_persistent),
                        hipFuncAttributeMaxDynamicSharedMemorySize,
                        DYN_LDS_BYTES);

    gru_persistent<<<BB, NT, DYN_LDS_BYTES, stream>>>(x, h0, Wir, Wiz, Win,
                                                      Whr, Whz, Whn,
                                                      bhr, bhz, bhn, Wd, bd, out);
}

// Round 9
// 1618.593 us; speedup vs baseline: 1.1270x; 1.0141x over previous
//
#include <hip/hip_runtime.h>
#include <math.h>

#define BB 256
#define TT 2048
#define FF 2
#define HH 128
#define OO 2
#define NT 768   // 12 waves: 3 gates x 2 column-halves x 2 waves(128 threads)

typedef _Float16 h2 __attribute__((ext_vector_type(2)));

__device__ __forceinline__ float fast_rcp(float x) { return __builtin_amdgcn_rcpf(x); }
__device__ __forceinline__ float sigmoid_f(float x) { return fast_rcp(1.0f + __expf(-x)); }
__device__ __forceinline__ float tanh_f(float x) { return 1.0f - 2.0f * fast_rcp(1.0f + __expf(2.0f * x)); }

__device__ __forceinline__ float dot2(unsigned int hv, h2 w, float acc) {
#if __has_builtin(__builtin_amdgcn_fdot2)
    return __builtin_amdgcn_fdot2(__builtin_bit_cast(h2, hv), w, acc, false);
#else
    const h2 h = __builtin_bit_cast(h2, hv);
    acc = fmaf((float)h[0], (float)w[0], acc);
    return fmaf((float)h[1], (float)w[1], acc);
#endif
}

// ---- 32 named packed-half2 weights: never an array, never address-taken ----
#define FORW32(M) \
  M(0)  M(1)  M(2)  M(3)  M(4)  M(5)  M(6)  M(7)  \
  M(8)  M(9)  M(10) M(11) M(12) M(13) M(14) M(15) \
  M(16) M(17) M(18) M(19) M(20) M(21) M(22) M(23) \
  M(24) M(25) M(26) M(27) M(28) M(29) M(30) M(31)

#define DECLW(i) h2 wp_##i;
#define LOADW(i) wp_##i[0] = (_Float16)Wcol[(c64 + 2*(i)    ) * HH]; \
                 wp_##i[1] = (_Float16)Wcol[(c64 + 2*(i) + 1) * HH];

// one uint4 LDS read = 8 halves of h -> 4 dot2 (8 MACs)
#define DOTQ(q, i0, i1, i2, i3)                       \
    {                                                 \
        const uint4 hv_ = hq[q];                      \
        a0 = dot2(hv_.x, wp_##i0, a0);                \
        a1 = dot2(hv_.y, wp_##i1, a1);                \
        a2 = dot2(hv_.z, wp_##i2, a2);                \
        a3 = dot2(hv_.w, wp_##i3, a3);                \
    }

__global__ __launch_bounds__(NT)
__attribute__((amdgpu_waves_per_eu(3, 3)))   // pin occupancy TARGET: 12-wave
                                             // block = exactly 3 waves/SIMD,
                                             // VGPR budget 512/3 ~ 170 -> no
                                             // incentive to spill weights
void gru_persistent(const float* __restrict__ x, const float* __restrict__ h0,
                    const float* __restrict__ Wir, const float* __restrict__ Wiz,
                    const float* __restrict__ Win, const float* __restrict__ Whr,
                    const float* __restrict__ Whz, const float* __restrict__ Whn,
                    const float* __restrict__ bhr, const float* __restrict__ bhz,
                    const float* __restrict__ bhn, const float* __restrict__ Wd,
                    const float* __restrict__ bd, float* __restrict__ out)
{
    // out layout: [carry B*H][y B*T*O]
    __shared__ float x_sh[TT * FF];                       // 16 KB
    __shared__ __align__(16) float    h_sh[HH];           // fp32 master h
    __shared__ __align__(16) _Float16 hh_sh[HH];          // fp16 copy for dots
    __shared__ float part[3][2][HH];                      // gate x half x j

    const int b    = blockIdx.x;
    const int tid  = threadIdx.x;
    const int g    = tid >> 8;          // 0:r 1:z 2:n   (4 waves per gate)
    const int c    = (tid >> 7) & 1;    // column half   (2 waves per half)
    const int j    = tid & (HH - 1);    // output column
    const int wv   = tid >> 6;          // wave id 0..11
    const int lane = tid & 63;
    const int c64  = c * 64;

    const float* Wh = (g == 0) ? Whr : (g == 1) ? Whz : Whn;
    const float* Wi = (g == 0) ? Wir : (g == 1) ? Wiz : Win;
    const float* bh = (g == 0) ? bhr : (g == 1) ? bhz : bhn;

    // half weight column, packed fp16: 32 VGPRs
    FORW32(DECLW)
    {
        const float* Wcol = Wh + j;     // column j, row stride HH
        FORW32(LOADW)
    }

    const float gbias = (c == 0) ? bh[j] : 0.0f;
    float wi0 = 0.0f, wi1 = 0.0f;
    if (c == 0 && g != 2) { wi0 = Wi[0 * HH + j]; wi1 = Wi[1 * HH + j]; }

    // combine-thread extras (tid < 128)
    float win0 = 0.0f, win1 = 0.0f;
    if (tid < HH) { win0 = Win[0 * HH + j]; win1 = Win[1 * HH + j]; }

    // y-wave (wave 8) extras: Wd columns for this lane's two h entries
    float wdA0 = 0.f, wdA1 = 0.f, wdB0 = 0.f, wdB1 = 0.f;
    if (wv == 8) {
        wdA0 = Wd[lane * OO + 0];        wdA1 = Wd[lane * OO + 1];
        wdB0 = Wd[(lane + 64) * OO + 0]; wdB1 = Wd[(lane + 64) * OO + 1];
    }
    const float bd0 = bd[0], bd1 = bd[1];

    // stage x row (float4) and h0 (fp32 + fp16 copy)
    {
        const float4* xi = reinterpret_cast<const float4*>(x + (size_t)b * TT * FF);
        float4* xo = reinterpret_cast<float4*>(x_sh);
        for (int i = tid; i < TT * FF / 4; i += NT) xo[i] = xi[i];
    }
    if (tid < HH) {
        const float hv = h0[b * HH + tid];
        h_sh[tid]  = hv;
        hh_sh[tid] = (_Float16)hv;
    }
    __syncthreads();

    float* __restrict__ yout = out + BB * HH;

    for (int t = 0; t < TT; ++t) {
        const float x0 = x_sh[t * FF + 0];
        const float x1 = x_sh[t * FF + 1];

        // ---- phase 1: per-gate half-column GEMV via v_dot2_f32_f16 ----
        float a0 = gbias + x0 * wi0 + x1 * wi1;   // wi==0 where not applicable
        float a1 = 0.f, a2 = 0.f, a3 = 0.f;
        // this thread's h slice: 64 halves = 8 x uint4 (uniform across wave)
        const uint4* hq = reinterpret_cast<const uint4*>(hh_sh) + (c << 3);
        DOTQ(0,  0,  1,  2,  3)
        DOTQ(1,  4,  5,  6,  7)
        DOTQ(2,  8,  9,  10, 11)
        DOTQ(3,  12, 13, 14, 15)
        DOTQ(4,  16, 17, 18, 19)
        DOTQ(5,  20, 21, 22, 23)
        DOTQ(6,  24, 25, 26, 27)
        DOTQ(7,  28, 29, 30, 31)
        part[g][c][j] = (a0 + a1) + (a2 + a3);

        // wave 8 additionally emits y[t-1] from h_sh (stable during phase 1)
        if (wv == 8 && t > 0) {
            const float hv0 = h_sh[lane], hv1 = h_sh[lane + 64];
            float p0 = hv0 * wdA0 + hv1 * wdB0;
            float p1 = hv0 * wdA1 + hv1 * wdB1;
            #pragma unroll
            for (int off = 32; off >= 1; off >>= 1) {
                p0 += __shfl_xor(p0, off);
                p1 += __shfl_xor(p1, off);
            }
            if (lane == 0)
                reinterpret_cast<float2*>(yout)[(size_t)b * TT + (t - 1)] =
                    make_float2(p0 + bd0, p1 + bd1);
        }
        __syncthreads();   // barrier A: partials visible

        // ---- phase 2: combine (threads 0..127), recurrence in fp32 ----
        if (tid < HH) {
            const float racc = part[0][0][j] + part[0][1][j];
            const float zacc = part[1][0][j] + part[1][1][j];
            const float macc = part[2][0][j] + part[2][1][j];
            const float r  = sigmoid_f(racc);
            const float z  = sigmoid_f(zacc);
            const float n  = tanh_f(x0 * win0 + x1 * win1 + r * macc);
            const float hn = (1.0f - z) * n + z * h_sh[j];
            h_sh[j]  = hn;
            hh_sh[j] = (_Float16)hn;
        }
        __syncthreads();   // barrier B: h_new visible
    }

    // tail: y[T-1] and carry
    if (wv == 8) {
        const float hv0 = h_sh[lane], hv1 = h_sh[lane + 64];
        float p0 = hv0 * wdA0 + hv1 * wdB0;
        float p1 = hv0 * wdA1 + hv1 * wdB1;
        #pragma unroll
        for (int off = 32; off >= 1; off >>= 1) {
            p0 += __shfl_xor(p0, off);
            p1 += __shfl_xor(p1, off);
        }
        if (lane == 0)
            reinterpret_cast<float2*>(yout)[(size_t)b * TT + (TT - 1)] =
                make_float2(p0 + bd0, p1 + bd1);
    }
    if (tid < HH) out[b * HH + tid] = h_sh[tid];
}

extern "C" void kernel_launch(void* const* d_in, const int* in_sizes, int n_in,
                              void* d_out, int out_size, void* d_ws, size_t ws_size,
                              hipStream_t stream) {
    const float* x   = (const float*)d_in[0];
    const float* h0  = (const float*)d_in[1];
    const float* Wir = (const float*)d_in[2];
    const float* Wiz = (const float*)d_in[3];
    const float* Win = (const float*)d_in[4];
    const float* Whr = (const float*)d_in[5];
    const float* Whz = (const float*)d_in[6];
    const float* Whn = (const float*)d_in[7];
    const float* bhr = (const float*)d_in[8];
    const float* bhz = (const float*)d_in[9];
    const float* bhn = (const float*)d_in[10];
    const float* Wd  = (const float*)d_in[11];
    const float* bd  = (const float*)d_in[12];
    float* out = (float*)d_out;

    gru_persistent<<<BB, NT, 0, stream>>>(x, h0, Wir, Wiz, Win, Whr, Whz, Whn,
                                          bhr, bhz, bhn, Wd, bd, out);
}